// Round 13
// baseline (251.944 us; speedup 1.0000x reference)
//
#include <hip/hip_runtime.h>

#define LTAG 64
#define BPB 16   // batch columns per block; grid = B/BPB = 16 blocks, 1 wave each
#define L2E 1.4426950408889634f
#define LN2 0.6931471805599453f

typedef float f32x4v __attribute__((ext_vector_type(4)));
typedef short s16x8 __attribute__((ext_vector_type(8)));
typedef int i32x4 __attribute__((ext_vector_type(4)));

__device__ __forceinline__ float exp2_fast(float x) { return __builtin_amdgcn_exp2f(x); }
__device__ __forceinline__ float log2_fast(float x) { return __builtin_amdgcn_logf(x); }
__device__ __forceinline__ int bperm_i(int abytes, int v) {
    return __builtin_amdgcn_ds_bpermute(abytes, v);
}
// bf16 pair pack, PURE INTEGER round-half-up (r10/r11/r12 post-mortem: the
// v_cvt_pk_bf16_f32 inline asm is the one instruction common to all three
// NaN rounds — replaced by known-good ALU ops; +0x8000 carry = correct
// round-up into the exponent; inputs are non-negative finite by design).
__device__ __forceinline__ int pack_bf16(float lo, float hi) {
    const unsigned ul = __float_as_uint(lo) + 0x8000u;
    const unsigned uh = __float_as_uint(hi) + 0x8000u;
    return (int)((ul >> 16) | (uh & 0xffff0000u));
}
__device__ __forceinline__ float bf16_lo(int w) { return __int_as_float(w << 16); }
__device__ __forceinline__ float bf16_hi(int w) {
    return __int_as_float((int)((unsigned)w & 0xffff0000u));
}

// ROUND-13 — batch-blocked MFMA recurrence, register-only repack (r12
// structure; cvt_pk asm removed, rescale clamped, x-ring static-indexed).
//
// Algorithm: E is batch-shared, so the MFMA N-dimension is the BATCH:
//   V: 64 prev-tags x 16 batches (exp domain, per-column shift SH_b)
//   V' = (E^T . V) (x) G,   G[n][b] = exp2(x_t[b][n]*L2E)
// A = E^T constant bf16 frags; B = V. 8 mfma_16x16x32_bf16 per step (4 row
// tiles x 2 K-slices chained). No redundant FLOPs (B*T*L^2 = 537M MACs).
//
// Layouts (16x16x32): D HW-verified [m89/m91]: lane(g,c) reg j = D[16RT+4g+j][c].
// A/B assumed std mapping [m92/m97-corroborated]: A: lane holds A[l&15][8g+e];
// B: lane holds B[8g+e][l&15]. If wrong -> FINITE wrong (diagnosable), since
// the rescale uses only the verified D layout.
//
// D->next-B repack, PURE REGISTERS: row 32KS+8g+e of B lives in D at lane
// g'=(2g+(e>>2))&3, reg j=e&3, tile RT=2KS+(g>>1) -> 8 integer packs +
// 16 ds_bpermute (step-invariant addresses, r9 HW-proven) + 8 cndmask.
// ZERO LDS / ZERO barriers in the loop (r11 lesson).
//
// x ring: distance 4, STATIC slots (4 named arrays, 4-substep unroll + tail)
// — registers, not scratch [rule #20]; refill AFTER consumption (r2 lesson).
// Per-column EXACT pow2 rescale every 4 steps: 16 local fmax + 2 shfl_xor
// (lanes sharing column c), eb clamped to [1,254] so the factor can never be
// inf/denormal. Final step t=T-1 in log domain with per-column c2 (tag-B
// exact via Etr[:,B]==1): one LDS dump guarded by a real __syncthreads().
__global__ __launch_bounds__(64) void crf_forward_kernel(
    const float* __restrict__ X, const float* __restrict__ trans,
    float* __restrict__ out, int T) {
    const int lane = threadIdx.x;
    const int c = lane & 15;   // batch column within block
    const int g = lane >> 4;   // 4-lane row group
    const int b0 = blockIdx.x * BPB;
    const size_t bstr = (size_t)T * LTAG;
    const float* xc = X + (size_t)(b0 + c) * bstr;  // this lane's batch stream

    // ---- constant A-frags: A[m][k] = E^T[m][k] = exp2(trans[k][m]*L2E) ----
    i32x4 Af[4][2];
#pragma unroll
    for (int RT = 0; RT < 4; ++RT)
#pragma unroll
        for (int KS = 0; KS < 2; ++KS) {
            int q[4];
#pragma unroll
            for (int i = 0; i < 4; ++i) {
                const int k0 = 32 * KS + 8 * g + 2 * i;
                const int m = 16 * RT + c;
                q[i] = pack_bf16(exp2_fast(trans[k0 * LTAG + m] * L2E),
                                 exp2_fast(trans[(k0 + 1) * LTAG + m] * L2E));
            }
            Af[RT][KS] = (i32x4){q[0], q[1], q[2], q[3]};
        }

    // ---- init B = V_1: V1[k][c] = exp2((trans[B_IDX=0][k] + x_0[c][k])*L2E) --
    i32x4 Bf[2];
#pragma unroll
    for (int KS = 0; KS < 2; ++KS) {
        int q[4];
#pragma unroll
        for (int i = 0; i < 4; ++i) {
            const int k0 = 32 * KS + 8 * g + 2 * i;
            q[i] = pack_bf16(exp2_fast((trans[k0] + xc[k0]) * L2E),
                             exp2_fast((trans[k0 + 1] + xc[k0 + 1]) * L2E));
        }
        Bf[KS] = (i32x4){q[0], q[1], q[2], q[3]};
    }

    // ---- x ring, distance 4, STATIC slots ----
    f32x4v xr0[4], xr1[4], xr2[4], xr3[4];
#pragma unroll
    for (int RT = 0; RT < 4; ++RT) {
        xr0[RT] = *(const f32x4v*)(xc + (size_t)1 * LTAG + 16 * RT + 4 * g);
        xr1[RT] = *(const f32x4v*)(xc + (size_t)2 * LTAG + 16 * RT + 4 * g);
        xr2[RT] = *(const f32x4v*)(xc + (size_t)3 * LTAG + 16 * RT + 4 * g);
        xr3[RT] = *(const f32x4v*)(xc + (size_t)4 * LTAG + 16 * RT + 4 * g);
    }

    // step-invariant bpermute addresses (source lanes for the repack)
    const int adrA = ((((2 * g) & 3) << 4) | c) << 2;
    const int adrB = ((((2 * g + 1) & 3) << 4) | c) << 2;
    float SH = 0.0f;

// one recurrence step t_ using x ring slot XR; RESC = do rescale
#define SUBSTEP(t_, XR, RESC)                                                 \
    {                                                                         \
        /* D = E^T * V : 4 independent 2-chains */                            \
        f32x4v acc[4];                                                        \
        _Pragma("unroll") for (int RT = 0; RT < 4; ++RT) {                    \
            f32x4v z = {0.f, 0.f, 0.f, 0.f};                                  \
            z = __builtin_amdgcn_mfma_f32_16x16x32_bf16(                      \
                __builtin_bit_cast(s16x8, Af[RT][0]),                         \
                __builtin_bit_cast(s16x8, Bf[0]), z, 0, 0, 0);                \
            acc[RT] = __builtin_amdgcn_mfma_f32_16x16x32_bf16(                \
                __builtin_bit_cast(s16x8, Af[RT][1]),                         \
                __builtin_bit_cast(s16x8, Bf[1]), z, 0, 0, 0);                \
        }                                                                     \
        /* G-scale: x loaded 4 steps ago; exp2 hoists under the MFMAs */      \
        _Pragma("unroll") for (int RT = 0; RT < 4; ++RT)                      \
        _Pragma("unroll") for (int j = 0; j < 4; ++j)                         \
            acc[RT][j] *= exp2_fast(XR[RT][j] * L2E);                         \
        /* ring refill AFTER consumption (distance 4) */                      \
        {                                                                     \
            int tp = (t_) + 4;                                                \
            tp = tp < T ? tp : T - 1;                                         \
            _Pragma("unroll") for (int RT = 0; RT < 4; ++RT)                  \
                XR[RT] = *(const f32x4v*)(xc + (size_t)tp * LTAG + 16 * RT +  \
                                          4 * g);                             \
        }                                                                     \
        if (RESC) {                                                           \
            /* per-column EXACT pow2 rescale (full column max via 2 shfl) */  \
            float m = acc[0][0];                                              \
            _Pragma("unroll") for (int RT = 0; RT < 4; ++RT)                  \
            _Pragma("unroll") for (int j = 0; j < 4; ++j)                     \
                m = fmaxf(m, acc[RT][j]);                                     \
            m = fmaxf(m, __shfl_xor(m, 16));                                  \
            m = fmaxf(m, __shfl_xor(m, 32));                                  \
            int eb = (__float_as_int(m) >> 23) & 0xff;                        \
            eb = eb < 1 ? 1 : (eb > 254 ? 254 : eb);  /* factor never inf */  \
            const float fac = __int_as_float((254 - eb) << 23);               \
            _Pragma("unroll") for (int RT = 0; RT < 4; ++RT)                  \
            _Pragma("unroll") for (int j = 0; j < 4; ++j) acc[RT][j] *= fac;  \
            SH += (float)(eb - 127);                                          \
        }                                                                     \
        /* repack D -> next B (registers only) */                             \
        int pk[4][2];                                                         \
        _Pragma("unroll") for (int RT = 0; RT < 4; ++RT) {                    \
            pk[RT][0] = pack_bf16(acc[RT][0], acc[RT][1]);                    \
            pk[RT][1] = pack_bf16(acc[RT][2], acc[RT][3]);                    \
        }                                                                     \
        _Pragma("unroll") for (int KS = 0; KS < 2; ++KS) {                    \
            const int ra0 = bperm_i(adrA, pk[2 * KS][0]);                     \
            const int ra1 = bperm_i(adrA, pk[2 * KS][1]);                     \
            const int ra2 = bperm_i(adrA, pk[2 * KS + 1][0]);                 \
            const int ra3 = bperm_i(adrA, pk[2 * KS + 1][1]);                 \
            const int rb0 = bperm_i(adrB, pk[2 * KS][0]);                     \
            const int rb1 = bperm_i(adrB, pk[2 * KS][1]);                     \
            const int rb2 = bperm_i(adrB, pk[2 * KS + 1][0]);                 \
            const int rb3 = bperm_i(adrB, pk[2 * KS + 1][1]);                 \
            const bool hi = g >= 2; /* RT select: 2KS vs 2KS+1 */             \
            Bf[KS] = (i32x4){hi ? ra2 : ra0, hi ? ra3 : ra1,                  \
                             hi ? rb2 : rb0, hi ? rb3 : rb1};                 \
        }                                                                     \
    }

    // main loop: groups of 4 (t starts at 1, so substep 3 has t%4==0)
    int t = 1;
    for (; t + 3 <= T - 2; t += 4) {
        SUBSTEP(t + 0, xr0, false);
        SUBSTEP(t + 1, xr1, false);
        SUBSTEP(t + 2, xr2, false);
        SUBSTEP(t + 3, xr3, true);
    }
    // tail (up to 3 steps; T=512 -> 2)
    if (t <= T - 2) { SUBSTEP(t, xr0, ((t & 3) == 0)); ++t; }
    if (t <= T - 2) { SUBSTEP(t, xr1, ((t & 3) == 0)); ++t; }
    if (t <= T - 2) { SUBSTEP(t, xr2, ((t & 3) == 0)); ++t; }
#undef SUBSTEP

    // ================= final step t = T-1 (log domain, c2) =================
    __shared__ __align__(16) short vl[BPB][80];  // V_{T-1} bf16, padded rows
    __shared__ float shl[BPB];
#pragma unroll
    for (int KS = 0; KS < 2; ++KS)
        *(i32x4*)(&vl[c][32 * KS + 8 * g]) = Bf[KS];
    shl[c] = SH;  // identical across the 4 lanes of column c
    __syncthreads();  // one-time; guards cross-lane LDS RAW (r11 lesson)

    const int n = lane;  // output tag
    float c2n = -3.0e38f;
#pragma unroll
    for (int p = 0; p < LTAG; ++p)
        c2n = fmaxf(c2n, trans[p * LTAG + n] * L2E);
    float er[LTAG];
#pragma unroll
    for (int p = 0; p < LTAG; ++p)
        er[p] = exp2_fast(trans[p * LTAG + n] * L2E - c2n);  // Etr[:,B]==1

    for (int b = 0; b < BPB; ++b) {
        float s0 = 0.f, s1 = 0.f, s2 = 0.f, s3 = 0.f;
#pragma unroll
        for (int p = 0; p < LTAG; p += 4) {
            const int w0 = *(const int*)(&vl[b][p]);  // uniform broadcast
            const int w1 = *(const int*)(&vl[b][p + 2]);
            s0 = fmaf(bf16_lo(w0), er[p + 0], s0);
            s1 = fmaf(bf16_hi(w0), er[p + 1], s1);
            s2 = fmaf(bf16_lo(w1), er[p + 2], s2);
            s3 = fmaf(bf16_hi(w1), er[p + 3], s3);
        }
        float s = (s0 + s1) + (s2 + s3);
        s = fmaxf(s, 1e-30f);  // keep a pathological column finite-diagnosable
        const float xl = X[(size_t)(b0 + b) * bstr + (size_t)(T - 1) * LTAG + n];
        out[(b0 + b) * LTAG + n] = (log2_fast(s) + fmaf(xl, L2E, c2n) + shl[b]) * LN2;
    }
}

extern "C" void kernel_launch(void* const* d_in, const int* in_sizes, int n_in,
                              void* d_out, int out_size, void* d_ws, size_t ws_size,
                              hipStream_t stream) {
    const float* X = (const float*)d_in[0];
    const float* trans = (const float*)d_in[1];
    float* out = (float*)d_out;

    const int B = out_size / LTAG;           // 256
    const int T = in_sizes[0] / (B * LTAG);  // 512

    crf_forward_kernel<<<B / BPB, 64, 0, stream>>>(X, trans, out, T);
}